// Round 9
// baseline (415.810 us; speedup 1.0000x reference)
//
#include <hip/hip_runtime.h>
#include <math.h>

// GCN forward, exact per-node CSR via bucket multisplit + split counting sort,
// fully-fused CSR-gather layers (4 lanes/node, zero f32 atomics).
// Pipeline: zero -> bhist -> bscan -> bucket (single-pass, register-buffered,
// EPB_B=8 so buffers stay in VGPRs) -> pcount/pscan/place2 (split per-bucket
// counting sort; NS slices per bucket) -> proj1 -> flayer x2 -> flayer3
// (+proba, mean partials) -> value.
// g = dis * (h @ W);  h_out[c] = relu( dis[c] * (sum_in g[row] + g[c]) + b )
// out[0..N-1] = proba, out[N] = value.

static constexpr int HDIM = 8;
#define EPB 16              // edges per thread in k_bhist
#define EPB_B 8             // edges per thread in k_bucket (register arrays)
#define MAXBUCK 512
#define NS 8                // slices per bucket in counting sort

// ---- zero bucket histogram; terminate noff ----
__global__ void k_zero(int* __restrict__ bhist, int* __restrict__ noff,
                       int nbuck, int n, int E) {
    int i = blockIdx.x * 256 + threadIdx.x;
    if (i < nbuck) bhist[i] = 0;
    if (i == 0) noff[n] = E;
}

// ---- per-bucket histogram ----
__global__ void k_bhist(const int* __restrict__ col, int E, int nbuck,
                        int* __restrict__ bhist) {
    __shared__ int lcnt[MAXBUCK];
    for (int b = threadIdx.x; b < nbuck; b += 256) lcnt[b] = 0;
    __syncthreads();
    int base = blockIdx.x * (256 * EPB);
#pragma unroll
    for (int k = 0; k < EPB; ++k) {
        int e = base + k * 256 + threadIdx.x;
        if (e < E) atomicAdd(&lcnt[col[e] >> 8], 1);
    }
    __syncthreads();
    for (int b = threadIdx.x; b < nbuck; b += 256) {
        int c = lcnt[b];
        if (c) atomicAdd(&bhist[b], c);
    }
}

// ---- scan bucket counts -> bbase, init bcur ----
__global__ void k_bscan(const int* __restrict__ bhist, int nbuck,
                        int* __restrict__ bbase, int* __restrict__ bcur) {
    __shared__ int ts[MAXBUCK];
    int t = threadIdx.x;
    ts[t] = (t < nbuck) ? bhist[t] : 0;
    __syncthreads();
    for (int d = 1; d < MAXBUCK; d <<= 1) {
        int v = ts[t];
        int add = (t >= d) ? ts[t - d] : 0;
        __syncthreads();
        ts[t] = v + add;
        __syncthreads();
    }
    int ex = (t == 0) ? 0 : ts[t - 1];
    if (t < nbuck) { bbase[t] = ex; bcur[t] = ex; }
    if (t == nbuck) bbase[t] = ts[nbuck - 1];
}

// ---- multisplit scatter: single pass, register-buffered (fits in VGPRs) ----
__global__ void __launch_bounds__(256, 8)
k_bucket(const int* __restrict__ row, const int* __restrict__ col,
         int E, int nbuck, int* __restrict__ bcur,
         unsigned* __restrict__ bedge) {
    __shared__ int lcnt[MAXBUCK];
    __shared__ int lbase[MAXBUCK];
    int t = threadIdx.x;
    for (int b = t; b < nbuck; b += 256) lcnt[b] = 0;
    __syncthreads();
    int base = blockIdx.x * (256 * EPB_B);
    int myb[EPB_B], myrank[EPB_B];
    unsigned myv[EPB_B];
#pragma unroll
    for (int k = 0; k < EPB_B; ++k) {
        int e = base + k * 256 + t;
        if (e < E) {
            int c = col[e];
            int b = c >> 8;
            myb[k] = b;
            myrank[k] = atomicAdd(&lcnt[b], 1);
            myv[k] = ((unsigned)row[e] << 8) | (unsigned)(c & 255);
        } else myb[k] = -1;
    }
    __syncthreads();
    for (int b = t; b < nbuck; b += 256) {
        int c = lcnt[b];
        lbase[b] = c ? atomicAdd(&bcur[b], c) : 0;
    }
    __syncthreads();
#pragma unroll
    for (int k = 0; k < EPB_B; ++k)
        if (myb[k] >= 0) bedge[lbase[myb[k]] + myrank[k]] = myv[k];
}

// ---- per-slice per-node histogram ----
__global__ void k_pcount(const int* __restrict__ bbase, const unsigned* __restrict__ bedge,
                         int* __restrict__ pcnt) {
    __shared__ int lcnt[256];
    int t = threadIdx.x;
    lcnt[t] = 0;
    __syncthreads();
    int b = blockIdx.x / NS, s = blockIdx.x % NS;
    int s0 = bbase[b], len = bbase[b + 1] - s0;
    int lo = s0 + (int)((long long)len * s / NS);
    int hi = s0 + (int)((long long)len * (s + 1) / NS);
    for (int p = lo + t; p < hi; p += 256) atomicAdd(&lcnt[bedge[p] & 255], 1);
    __syncthreads();
    pcnt[(size_t)blockIdx.x * 256 + t] = lcnt[t];
}

// ---- per-bucket scan: noff, dis, per-slice cursors ----
__global__ void k_pscan(const int* __restrict__ bbase, const int* __restrict__ pcnt,
                        int* __restrict__ scur, int* __restrict__ noff,
                        float* __restrict__ dis, int n) {
    __shared__ int ts[256];
    int t = threadIdx.x, b = blockIdx.x;
    int c[NS];
    int tot = 0;
#pragma unroll
    for (int s = 0; s < NS; ++s) {
        c[s] = pcnt[((size_t)b * NS + s) * 256 + t];
        tot += c[s];
    }
    ts[t] = tot;
    __syncthreads();
    for (int d = 1; d < 256; d <<= 1) {
        int v = ts[t];
        int add = (t >= d) ? ts[t - d] : 0;
        __syncthreads();
        ts[t] = v + add;
        __syncthreads();
    }
    int start = bbase[b] + ts[t] - tot;     // exclusive scan
    int i = (b << 8) + t;
    if (i < n) {
        noff[i] = start;
        dis[i] = rsqrtf((float)(tot + 1));  // +1 self loop
    }
    int run = start;
#pragma unroll
    for (int s = 0; s < NS; ++s) {
        scur[((size_t)b * NS + s) * 256 + t] = run;
        run += c[s];
    }
}

// ---- slice placement: perm[pos] = row, dest-sorted ----
__global__ void k_place2(const int* __restrict__ bbase, const unsigned* __restrict__ bedge,
                         const int* __restrict__ scur, int* __restrict__ perm) {
    __shared__ int lcur[256];
    int t = threadIdx.x;
    int b = blockIdx.x / NS, s = blockIdx.x % NS;
    lcur[t] = scur[(size_t)blockIdx.x * 256 + t];
    __syncthreads();
    int s0 = bbase[b], len = bbase[b + 1] - s0;
    int lo = s0 + (int)((long long)len * s / NS);
    int hi = s0 + (int)((long long)len * (s + 1) / NS);
    for (int p = lo + t; p < hi; p += 256) {
        unsigned v = bedge[p];
        int lc = (int)(v & 255);
        int pos = atomicAdd(&lcur[lc], 1);
        perm[pos] = (int)(v >> 8);
    }
}

// ---- layer-1 projection, 4 threads/node: g = dis * (x @ W1) ----
__global__ void k_proj1(const float* __restrict__ x, const float* __restrict__ W1,
                        const float* __restrict__ dis, float* __restrict__ g, int n) {
    __shared__ float Ws[32 * 36];          // chunk-padded: [c][j][r], stride 36
    const float4* Ws4 = (const float4*)Ws;
    for (int t = threadIdx.x; t < 1024; t += 256) {
        int c = t >> 5, rem = t & 31, j = rem >> 2, r = rem & 3;
        Ws[c * 36 + j * 4 + r] = W1[(c * 4 + r) * 8 + j];
    }
    __syncthreads();
    int t4 = blockIdx.x * blockDim.x + threadIdx.x;
    int i = t4 >> 2, sub = t4 & 3;
    if (i >= n) return;
    const float4* x4 = (const float4*)x;
    float a[HDIM] = {0, 0, 0, 0, 0, 0, 0, 0};
#pragma unroll
    for (int iter = 0; iter < 8; ++iter) {
        int c = iter * 4 + sub;
        float4 xv = x4[(size_t)i * 32 + c];
#pragma unroll
        for (int j = 0; j < HDIM; ++j) {
            float4 wv = Ws4[c * 9 + j];
            a[j] += xv.x * wv.x + xv.y * wv.y + xv.z * wv.z + xv.w * wv.w;
        }
    }
#pragma unroll
    for (int j = 0; j < HDIM; ++j) {
        a[j] += __shfl_xor(a[j], 1);
        a[j] += __shfl_xor(a[j], 2);
    }
    float di = dis[i];
    float4* gp = (float4*)(g + (size_t)i * HDIM);
    if (sub == 0) gp[0] = make_float4(di * a[0], di * a[1], di * a[2], di * a[3]);
    if (sub == 1) gp[1] = make_float4(di * a[4], di * a[5], di * a[6], di * a[7]);
}

// ---- fused mid layer: CSR gather (4 lanes/node) + relu + next projection ----
__global__ void k_flayer(const int* __restrict__ noff, const int* __restrict__ perm,
                         const float* __restrict__ g_in, float* __restrict__ g_out,
                         const float* __restrict__ dis, const float* __restrict__ bias,
                         const float* __restrict__ Wn, int n) {
    __shared__ float Ws[HDIM * HDIM];
    __shared__ float bs[HDIM];
    int t = threadIdx.x;
    if (t < HDIM * HDIM) Ws[t] = Wn[t];
    if (t < HDIM) bs[t] = bias[t];
    __syncthreads();
    int q = t >> 2, sub = t & 3;
    int i = blockIdx.x * 64 + q;
    if (i >= n) return;
    int s = noff[i], e = noff[i + 1];
    const float4* g4 = (const float4*)g_in;
    float a[HDIM] = {0, 0, 0, 0, 0, 0, 0, 0};
    int p = s + sub;
    for (; p + 4 < e; p += 8) {
        int r0 = perm[p], r1 = perm[p + 4];
        float4 u0 = g4[(size_t)r0 * 2], v0 = g4[(size_t)r0 * 2 + 1];
        float4 u1 = g4[(size_t)r1 * 2], v1 = g4[(size_t)r1 * 2 + 1];
        a[0] += u0.x + u1.x; a[1] += u0.y + u1.y;
        a[2] += u0.z + u1.z; a[3] += u0.w + u1.w;
        a[4] += v0.x + v1.x; a[5] += v0.y + v1.y;
        a[6] += v0.z + v1.z; a[7] += v0.w + v1.w;
    }
    if (p < e) {
        int r = perm[p];
        float4 u = g4[(size_t)r * 2], v = g4[(size_t)r * 2 + 1];
        a[0] += u.x; a[1] += u.y; a[2] += u.z; a[3] += u.w;
        a[4] += v.x; a[5] += v.y; a[6] += v.z; a[7] += v.w;
    }
#pragma unroll
    for (int j = 0; j < HDIM; ++j) {
        a[j] += __shfl_xor(a[j], 1);
        a[j] += __shfl_xor(a[j], 2);
    }
    float di = dis[i];
    float4 s0 = g4[(size_t)i * 2], s1 = g4[(size_t)i * 2 + 1];   // self term
    float h[HDIM];
    h[0] = fmaxf(di * (a[0] + s0.x) + bs[0], 0.0f);
    h[1] = fmaxf(di * (a[1] + s0.y) + bs[1], 0.0f);
    h[2] = fmaxf(di * (a[2] + s0.z) + bs[2], 0.0f);
    h[3] = fmaxf(di * (a[3] + s0.w) + bs[3], 0.0f);
    h[4] = fmaxf(di * (a[4] + s1.x) + bs[4], 0.0f);
    h[5] = fmaxf(di * (a[5] + s1.y) + bs[5], 0.0f);
    h[6] = fmaxf(di * (a[6] + s1.z) + bs[6], 0.0f);
    h[7] = fmaxf(di * (a[7] + s1.w) + bs[7], 0.0f);
    int j0 = sub * 2;
    float gn0 = 0.0f, gn1 = 0.0f;
#pragma unroll
    for (int k = 0; k < HDIM; ++k) {
        gn0 += h[k] * Ws[k * HDIM + j0];
        gn1 += h[k] * Ws[k * HDIM + j0 + 1];
    }
    ((float2*)g_out)[(size_t)i * 4 + sub] = make_float2(di * gn0, di * gn1);
}

// ---- fused last layer: gather + relu + proba head + per-block mean partial ----
__global__ void k_flayer3(const int* __restrict__ noff, const int* __restrict__ perm,
                          const float* __restrict__ g_in, const float* __restrict__ dis,
                          const float* __restrict__ b3, const float* __restrict__ Wp,
                          const float* __restrict__ bp, float* __restrict__ out,
                          float* __restrict__ partial, int n) {
    __shared__ float red[4][HDIM];
    int t = threadIdx.x;
    int q = t >> 2, sub = t & 3;
    int i = blockIdx.x * 64 + q;
    bool valid = i < n;
    const float4* g4 = (const float4*)g_in;
    float a[HDIM] = {0, 0, 0, 0, 0, 0, 0, 0};
    if (valid) {
        int s = noff[i], e = noff[i + 1];
        int p = s + sub;
        for (; p + 4 < e; p += 8) {
            int r0 = perm[p], r1 = perm[p + 4];
            float4 u0 = g4[(size_t)r0 * 2], v0 = g4[(size_t)r0 * 2 + 1];
            float4 u1 = g4[(size_t)r1 * 2], v1 = g4[(size_t)r1 * 2 + 1];
            a[0] += u0.x + u1.x; a[1] += u0.y + u1.y;
            a[2] += u0.z + u1.z; a[3] += u0.w + u1.w;
            a[4] += v0.x + v1.x; a[5] += v0.y + v1.y;
            a[6] += v0.z + v1.z; a[7] += v0.w + v1.w;
        }
        if (p < e) {
            int r = perm[p];
            float4 u = g4[(size_t)r * 2], v = g4[(size_t)r * 2 + 1];
            a[0] += u.x; a[1] += u.y; a[2] += u.z; a[3] += u.w;
            a[4] += v.x; a[5] += v.y; a[6] += v.z; a[7] += v.w;
        }
    }
#pragma unroll
    for (int j = 0; j < HDIM; ++j) {
        a[j] += __shfl_xor(a[j], 1);
        a[j] += __shfl_xor(a[j], 2);
    }
    float h[HDIM] = {0, 0, 0, 0, 0, 0, 0, 0};
    if (valid) {
        float di = dis[i];
        float4 s0 = g4[(size_t)i * 2], s1 = g4[(size_t)i * 2 + 1];
        h[0] = fmaxf(di * (a[0] + s0.x) + b3[0], 0.0f);
        h[1] = fmaxf(di * (a[1] + s0.y) + b3[1], 0.0f);
        h[2] = fmaxf(di * (a[2] + s0.z) + b3[2], 0.0f);
        h[3] = fmaxf(di * (a[3] + s0.w) + b3[3], 0.0f);
        h[4] = fmaxf(di * (a[4] + s1.x) + b3[4], 0.0f);
        h[5] = fmaxf(di * (a[5] + s1.y) + b3[5], 0.0f);
        h[6] = fmaxf(di * (a[6] + s1.z) + b3[6], 0.0f);
        h[7] = fmaxf(di * (a[7] + s1.w) + b3[7], 0.0f);
        if (sub == 0) {
            float p = bp[0];
#pragma unroll
            for (int j = 0; j < HDIM; ++j) p += h[j] * Wp[j];
            out[i] = p;
        }
    }
    int w = t >> 6, lane = t & 63;
#pragma unroll
    for (int j = 0; j < HDIM; ++j) {
        float sj = (sub == 0) ? h[j] : 0.0f;
#pragma unroll
        for (int o = 32; o > 0; o >>= 1) sj += __shfl_down(sj, o);
        if (lane == 0) red[w][j] = sj;
    }
    __syncthreads();
    if (t < HDIM)
        partial[(size_t)blockIdx.x * HDIM + t] =
            red[0][t] + red[1][t] + red[2][t] + red[3][t];
}

// ---- value head: reduce per-block partials ----
__global__ void k_value(const float* __restrict__ partial, int nblocks,
                        const float* __restrict__ Wv, const float* __restrict__ bv,
                        float* __restrict__ out, int n) {
    __shared__ float red[256];
    int t = threadIdx.x;
    int j = t & 7, c = t >> 3;
    float v = 0.0f;
    for (int b = c; b < nblocks; b += 32) v += partial[(size_t)b * HDIM + j];
    red[t] = v;
    __syncthreads();
    for (int d = 128; d >= 8; d >>= 1) {
        if (t < d) red[t] += red[t + d];
        __syncthreads();
    }
    if (t == 0) {
        float val = bv[0];
        float inv_n = 1.0f / (float)n;
#pragma unroll
        for (int jj = 0; jj < HDIM; ++jj) val += (red[jj] * inv_n) * Wv[jj];
        out[n] = val;
    }
}

extern "C" void kernel_launch(void* const* d_in, const int* in_sizes, int n_in,
                              void* d_out, int out_size, void* d_ws, size_t ws_size,
                              hipStream_t stream) {
    const float* x  = (const float*)d_in[0];
    const int*   ei = (const int*)d_in[1];
    const float* W1 = (const float*)d_in[2];
    const float* b1 = (const float*)d_in[3];
    const float* W2 = (const float*)d_in[4];
    const float* b2 = (const float*)d_in[5];
    const float* W3 = (const float*)d_in[6];
    const float* b3 = (const float*)d_in[7];
    const float* Wp = (const float*)d_in[8];
    const float* bp = (const float*)d_in[9];
    const float* Wv = (const float*)d_in[10];
    const float* bv = (const float*)d_in[11];

    const int n = in_sizes[0] / 128;
    const int E = in_sizes[1] / 2;
    const int* row = ei;       // edge_index[0] = source
    const int* col = ei + E;   // edge_index[1] = target
    const int nbuck = (n + 255) >> 8;

    // workspace layout (4-byte units); ~59 MB total
    int*      bhist = (int*)d_ws;                   // 512
    int*      bbase = bhist + 512;                  // 512
    int*      bcur  = bhist + 1024;                 // 512 (ends 1536; pad to 6144)
    float*    dis   = (float*)(bhist + 6144);       // n
    int*      noff  = (int*)(dis + n);              // n+4 (padded)
    unsigned* bedge = (unsigned*)(noff + n + 4);    // E
    int*      perm  = (int*)(bedge + E);            // E
    float*    g_a   = (float*)(perm + E);           // n*8 (16B aligned)
    float*    g_b   = g_a + (size_t)n * HDIM;       // n*8
    float*    partial = g_b + (size_t)n * HDIM;     // ceil(n/64)*8
    // pcnt/scur alias g region (dead until proj1)
    int*      pcnt  = (int*)g_a;                    // nbuck*NS*256
    int*      scur  = pcnt + (size_t)nbuck * NS * 256;  // nbuck*NS*256

    dim3 blk(256);
    dim3 grid_n4(((size_t)n * 4 + 255) / 256);
    dim3 grid_e((E + 256 * EPB - 1) / (256 * EPB));
    dim3 grid_eb((E + 256 * EPB_B - 1) / (256 * EPB_B));
    dim3 grid_b(nbuck);
    dim3 grid_bs(nbuck * NS);
    dim3 grid_f((n + 63) / 64);
    const int nblocks3 = (n + 63) / 64;

    k_zero  <<<dim3((nbuck + 255) / 256), blk, 0, stream>>>(bhist, noff, nbuck, n, E);
    k_bhist <<<grid_e, blk, 0, stream>>>(col, E, nbuck, bhist);
    k_bscan <<<dim3(1), dim3(MAXBUCK), 0, stream>>>(bhist, nbuck, bbase, bcur);
    k_bucket<<<grid_eb, blk, 0, stream>>>(row, col, E, nbuck, bcur, bedge);
    k_pcount<<<grid_bs, blk, 0, stream>>>(bbase, bedge, pcnt);
    k_pscan <<<grid_b, blk, 0, stream>>>(bbase, pcnt, scur, noff, dis, n);
    k_place2<<<grid_bs, blk, 0, stream>>>(bbase, bedge, scur, perm);
    k_proj1 <<<grid_n4, blk, 0, stream>>>(x, W1, dis, g_a, n);

    k_flayer<<<grid_f, blk, 0, stream>>>(noff, perm, g_a, g_b, dis, b1, W2, n);
    k_flayer<<<grid_f, blk, 0, stream>>>(noff, perm, g_b, g_a, dis, b2, W3, n);
    k_flayer3<<<grid_f, blk, 0, stream>>>(noff, perm, g_a, dis, b3, Wp, bp,
                                          (float*)d_out, partial, n);
    k_value <<<dim3(1), blk, 0, stream>>>(partial, nblocks3, Wv, bv,
                                          (float*)d_out, n);
}

// Round 10
// 347.512 us; speedup vs baseline: 1.1965x; 1.1965x over previous
//
#include <hip/hip_runtime.h>
#include <math.h>

// GCN forward. Build: bucket multisplit into 1024-node buckets (long write
// runs), then per-chunk LDS counting sort IN PLACE (coalesced writeback).
// Per node, edges end up in <= NS runs; runs' starts/counts in scur/cnt.
// Layers: fused CSR-gather (4 lanes/node, 2 runs/lane), relu, next 8x8 proj.
// Zero f32 global atomics anywhere.
// g = dis * (h @ W);  h_out[c] = relu( dis[c] * (sum_in g[row] + g[c]) + b )
// out[0..N-1] = proba, out[N] = value.

static constexpr int HDIM = 8;
#define EPB 16              // edges/thread in k_bhist
#define EPB_B 16            // edges/thread in k_bucket (R7-measured best)
#define NBMAX 128           // >= nbuck (98)
#define NS 8                // chunks per bucket
#define BSH 10              // log2(bucket size)
#define BSZ 1024            // nodes per bucket
#define STG 10240           // sort staging entries (chunk <= ~8400)

// ---- zero deg + bucket histogram ----
__global__ void k_zero(int* __restrict__ deg, int* __restrict__ bhist,
                       int n, int nbuck) {
    int i = blockIdx.x * 256 + threadIdx.x;
    if (i < n) deg[i] = 0;
    if (i < nbuck) bhist[i] = 0;
}

// ---- per-bucket histogram ----
__global__ void k_bhist(const int* __restrict__ col, int E, int nbuck,
                        int* __restrict__ bhist) {
    __shared__ int lcnt[NBMAX];
    int t = threadIdx.x;
    if (t < nbuck) lcnt[t] = 0;
    __syncthreads();
    int base = blockIdx.x * (256 * EPB);
#pragma unroll
    for (int k = 0; k < EPB; ++k) {
        int e = base + k * 256 + t;
        if (e < E) atomicAdd(&lcnt[col[e] >> BSH], 1);
    }
    __syncthreads();
    if (t < nbuck) {
        int c = lcnt[t];
        if (c) atomicAdd(&bhist[t], c);
    }
}

// ---- scan bucket counts -> bbase, init bcur ----
__global__ void k_bscan(const int* __restrict__ bhist, int nbuck,
                        int* __restrict__ bbase, int* __restrict__ bcur) {
    __shared__ int ts[NBMAX];
    int t = threadIdx.x;
    ts[t] = (t < nbuck) ? bhist[t] : 0;
    __syncthreads();
    for (int d = 1; d < NBMAX; d <<= 1) {
        int v = ts[t];
        int add = (t >= d) ? ts[t - d] : 0;
        __syncthreads();
        ts[t] = v + add;
        __syncthreads();
    }
    int ex = (t == 0) ? 0 : ts[t - 1];
    if (t < nbuck) { bbase[t] = ex; bcur[t] = ex; }
    if (t == nbuck) bbase[t] = ts[nbuck - 1];
}

// ---- multisplit scatter: single pass, R7 structure, 98 buckets ----
__global__ void k_bucket(const int* __restrict__ row, const int* __restrict__ col,
                         int E, int nbuck, int* __restrict__ bcur,
                         unsigned* __restrict__ bedge) {
    __shared__ int lcnt[NBMAX];
    __shared__ int lbase[NBMAX];
    int t = threadIdx.x;
    if (t < nbuck) lcnt[t] = 0;
    __syncthreads();
    int base = blockIdx.x * (256 * EPB_B);
    int myb[EPB_B], myrank[EPB_B];
    unsigned myv[EPB_B];
#pragma unroll
    for (int k = 0; k < EPB_B; ++k) {
        int e = base + k * 256 + t;
        if (e < E) {
            int c = col[e];
            int b = c >> BSH;
            myb[k] = b;
            myrank[k] = atomicAdd(&lcnt[b], 1);
            myv[k] = ((unsigned)row[e] << BSH) | (unsigned)(c & (BSZ - 1));
        } else myb[k] = -1;
    }
    __syncthreads();
    if (t < nbuck) {
        int c = lcnt[t];
        lbase[t] = c ? atomicAdd(&bcur[t], c) : 0;
    }
    __syncthreads();
#pragma unroll
    for (int k = 0; k < EPB_B; ++k)
        if (myb[k] >= 0) bedge[lbase[myb[k]] + myrank[k]] = myv[k];
}

// ---- per-chunk LDS counting sort, in-place coalesced writeback ----
// bedge chunk (packed (row<<10)|lc) -> sorted-by-lc plain row values.
// Emits scur/cnt per (chunk, local node) and accumulates deg.
__global__ void k_sortchunk(const int* __restrict__ bbase, unsigned* __restrict__ bedge,
                            int* __restrict__ scur, int* __restrict__ cnt,
                            int* __restrict__ deg) {
    __shared__ int hist[BSZ];
    __shared__ int basec[BSZ];
    __shared__ int stag[STG];
    int t = threadIdx.x;
    int b = blockIdx.x / NS, s = blockIdx.x % NS;
    int s0 = bbase[b], len = bbase[b + 1] - s0;
    int lo = s0 + (int)((long long)len * s / NS);
    int hi = s0 + (int)((long long)len * (s + 1) / NS);
    int m = hi - lo;
    for (int q = t; q < BSZ; q += 256) hist[q] = 0;
    __syncthreads();
    for (int p = lo + t; p < hi; p += 256) atomicAdd(&hist[bedge[p] & (BSZ - 1)], 1);
    __syncthreads();
    // exclusive scan of hist (4 per thread) -> basec
    int v0 = hist[t * 4], v1 = hist[t * 4 + 1], v2 = hist[t * 4 + 2], v3 = hist[t * 4 + 3];
    int sum = v0 + v1 + v2 + v3;
    stag[t] = sum;
    __syncthreads();
    for (int d = 1; d < 256; d <<= 1) {
        int x = stag[t];
        int a = (t >= d) ? stag[t - d] : 0;
        __syncthreads();
        stag[t] = x + a;
        __syncthreads();
    }
    int run = (t == 0) ? 0 : stag[t - 1];
    basec[t * 4] = run;
    basec[t * 4 + 1] = run + v0;
    basec[t * 4 + 2] = run + v0 + v1;
    basec[t * 4 + 3] = run + v0 + v1 + v2;
    __syncthreads();
    // per-node outputs (before cursors are consumed)
    size_t obase = (size_t)blockIdx.x * BSZ;
    int gb = b << BSH;
#pragma unroll
    for (int q = 0; q < 4; ++q) {
        int lc = t * 4 + q;
        int h = hist[lc];
        scur[obase + lc] = lo + basec[lc];
        cnt[obase + lc] = h;
        if (h) atomicAdd(&deg[gb + lc], h);
    }
    __syncthreads();
    // place rows into staging at sorted positions (basec as cursors)
    for (int p = lo + t; p < hi; p += 256) {
        unsigned e = bedge[p];
        int pos = atomicAdd(&basec[e & (BSZ - 1)], 1);
        stag[pos] = (int)(e >> BSH);
    }
    __syncthreads();
    // coalesced in-place writeback
    for (int p = t; p < m; p += 256) bedge[lo + p] = (unsigned)stag[p];
}

// ---- layer-1 projection, 4 threads/node: dis = rsqrt(deg+1); g = dis*(x@W1) ----
__global__ void k_proj1(const float* __restrict__ x, const float* __restrict__ W1,
                        const int* __restrict__ deg, float* __restrict__ dis,
                        float* __restrict__ g, int n) {
    __shared__ float Ws[32 * 36];          // chunk-padded: [c][j][r], stride 36
    const float4* Ws4 = (const float4*)Ws;
    for (int t = threadIdx.x; t < 1024; t += 256) {
        int c = t >> 5, rem = t & 31, j = rem >> 2, r = rem & 3;
        Ws[c * 36 + j * 4 + r] = W1[(c * 4 + r) * 8 + j];
    }
    __syncthreads();
    int t4 = blockIdx.x * blockDim.x + threadIdx.x;
    int i = t4 >> 2, sub = t4 & 3;
    if (i >= n) return;
    const float4* x4 = (const float4*)x;
    float a[HDIM] = {0, 0, 0, 0, 0, 0, 0, 0};
#pragma unroll
    for (int iter = 0; iter < 8; ++iter) {
        int c = iter * 4 + sub;
        float4 xv = x4[(size_t)i * 32 + c];
#pragma unroll
        for (int j = 0; j < HDIM; ++j) {
            float4 wv = Ws4[c * 9 + j];
            a[j] += xv.x * wv.x + xv.y * wv.y + xv.z * wv.z + xv.w * wv.w;
        }
    }
#pragma unroll
    for (int j = 0; j < HDIM; ++j) {
        a[j] += __shfl_xor(a[j], 1);
        a[j] += __shfl_xor(a[j], 2);
    }
    float di = rsqrtf((float)(deg[i] + 1));   // +1 self loop
    if (sub == 2) dis[i] = di;
    float4* gp = (float4*)(g + (size_t)i * HDIM);
    if (sub == 0) gp[0] = make_float4(di * a[0], di * a[1], di * a[2], di * a[3]);
    if (sub == 1) gp[1] = make_float4(di * a[4], di * a[5], di * a[6], di * a[7]);
}

// ---- fused mid layer: multi-run gather (4 lanes/node, 2 runs/lane) ----
__global__ void k_flayer(const int* __restrict__ scur, const int* __restrict__ cnt,
                         const int* __restrict__ perm,
                         const float* __restrict__ g_in, float* __restrict__ g_out,
                         const float* __restrict__ dis, const float* __restrict__ bias,
                         const float* __restrict__ Wn, int n) {
    __shared__ float Ws[HDIM * HDIM];
    __shared__ float bs[HDIM];
    int t = threadIdx.x;
    if (t < HDIM * HDIM) Ws[t] = Wn[t];
    if (t < HDIM) bs[t] = bias[t];
    __syncthreads();
    int q = t >> 2, sub = t & 3;
    int i = blockIdx.x * 64 + q;
    if (i >= n) return;
    int bkt = i >> BSH, lc = i & (BSZ - 1);
    size_t rbase = ((size_t)bkt * NS) * BSZ + lc;
    const float4* g4 = (const float4*)g_in;
    float a[HDIM] = {0, 0, 0, 0, 0, 0, 0, 0};
#pragma unroll
    for (int ss = 0; ss < 2; ++ss) {
        int sl = sub + ss * 4;
        int st = scur[rbase + (size_t)sl * BSZ];
        int c = cnt[rbase + (size_t)sl * BSZ];
        int p = st, e = st + c;
        for (; p + 1 < e; p += 2) {
            int r0 = perm[p], r1 = perm[p + 1];
            float4 u0 = g4[(size_t)r0 * 2], w0 = g4[(size_t)r0 * 2 + 1];
            float4 u1 = g4[(size_t)r1 * 2], w1 = g4[(size_t)r1 * 2 + 1];
            a[0] += u0.x + u1.x; a[1] += u0.y + u1.y;
            a[2] += u0.z + u1.z; a[3] += u0.w + u1.w;
            a[4] += w0.x + w1.x; a[5] += w0.y + w1.y;
            a[6] += w0.z + w1.z; a[7] += w0.w + w1.w;
        }
        if (p < e) {
            int r = perm[p];
            float4 u = g4[(size_t)r * 2], w = g4[(size_t)r * 2 + 1];
            a[0] += u.x; a[1] += u.y; a[2] += u.z; a[3] += u.w;
            a[4] += w.x; a[5] += w.y; a[6] += w.z; a[7] += w.w;
        }
    }
#pragma unroll
    for (int j = 0; j < HDIM; ++j) {
        a[j] += __shfl_xor(a[j], 1);
        a[j] += __shfl_xor(a[j], 2);
    }
    float di = dis[i];
    float4 s0 = g4[(size_t)i * 2], s1 = g4[(size_t)i * 2 + 1];   // self term
    float h[HDIM];
    h[0] = fmaxf(di * (a[0] + s0.x) + bs[0], 0.0f);
    h[1] = fmaxf(di * (a[1] + s0.y) + bs[1], 0.0f);
    h[2] = fmaxf(di * (a[2] + s0.z) + bs[2], 0.0f);
    h[3] = fmaxf(di * (a[3] + s0.w) + bs[3], 0.0f);
    h[4] = fmaxf(di * (a[4] + s1.x) + bs[4], 0.0f);
    h[5] = fmaxf(di * (a[5] + s1.y) + bs[5], 0.0f);
    h[6] = fmaxf(di * (a[6] + s1.z) + bs[6], 0.0f);
    h[7] = fmaxf(di * (a[7] + s1.w) + bs[7], 0.0f);
    int j0 = sub * 2;
    float gn0 = 0.0f, gn1 = 0.0f;
#pragma unroll
    for (int k = 0; k < HDIM; ++k) {
        gn0 += h[k] * Ws[k * HDIM + j0];
        gn1 += h[k] * Ws[k * HDIM + j0 + 1];
    }
    ((float2*)g_out)[(size_t)i * 4 + sub] = make_float2(di * gn0, di * gn1);
}

// ---- fused last layer: + proba head + per-block mean partial ----
__global__ void k_flayer3(const int* __restrict__ scur, const int* __restrict__ cnt,
                          const int* __restrict__ perm,
                          const float* __restrict__ g_in, const float* __restrict__ dis,
                          const float* __restrict__ b3, const float* __restrict__ Wp,
                          const float* __restrict__ bp, float* __restrict__ out,
                          float* __restrict__ partial, int n) {
    __shared__ float red[4][HDIM];
    int t = threadIdx.x;
    int q = t >> 2, sub = t & 3;
    int i = blockIdx.x * 64 + q;
    bool valid = i < n;
    const float4* g4 = (const float4*)g_in;
    float a[HDIM] = {0, 0, 0, 0, 0, 0, 0, 0};
    if (valid) {
        int bkt = i >> BSH, lc = i & (BSZ - 1);
        size_t rbase = ((size_t)bkt * NS) * BSZ + lc;
#pragma unroll
        for (int ss = 0; ss < 2; ++ss) {
            int sl = sub + ss * 4;
            int st = scur[rbase + (size_t)sl * BSZ];
            int c = cnt[rbase + (size_t)sl * BSZ];
            int p = st, e = st + c;
            for (; p + 1 < e; p += 2) {
                int r0 = perm[p], r1 = perm[p + 1];
                float4 u0 = g4[(size_t)r0 * 2], w0 = g4[(size_t)r0 * 2 + 1];
                float4 u1 = g4[(size_t)r1 * 2], w1 = g4[(size_t)r1 * 2 + 1];
                a[0] += u0.x + u1.x; a[1] += u0.y + u1.y;
                a[2] += u0.z + u1.z; a[3] += u0.w + u1.w;
                a[4] += w0.x + w1.x; a[5] += w0.y + w1.y;
                a[6] += w0.z + w1.z; a[7] += w0.w + w1.w;
            }
            if (p < e) {
                int r = perm[p];
                float4 u = g4[(size_t)r * 2], w = g4[(size_t)r * 2 + 1];
                a[0] += u.x; a[1] += u.y; a[2] += u.z; a[3] += u.w;
                a[4] += w.x; a[5] += w.y; a[6] += w.z; a[7] += w.w;
            }
        }
    }
#pragma unroll
    for (int j = 0; j < HDIM; ++j) {
        a[j] += __shfl_xor(a[j], 1);
        a[j] += __shfl_xor(a[j], 2);
    }
    float h[HDIM] = {0, 0, 0, 0, 0, 0, 0, 0};
    if (valid) {
        float di = dis[i];
        float4 s0 = g4[(size_t)i * 2], s1 = g4[(size_t)i * 2 + 1];
        h[0] = fmaxf(di * (a[0] + s0.x) + b3[0], 0.0f);
        h[1] = fmaxf(di * (a[1] + s0.y) + b3[1], 0.0f);
        h[2] = fmaxf(di * (a[2] + s0.z) + b3[2], 0.0f);
        h[3] = fmaxf(di * (a[3] + s0.w) + b3[3], 0.0f);
        h[4] = fmaxf(di * (a[4] + s1.x) + b3[4], 0.0f);
        h[5] = fmaxf(di * (a[5] + s1.y) + b3[5], 0.0f);
        h[6] = fmaxf(di * (a[6] + s1.z) + b3[6], 0.0f);
        h[7] = fmaxf(di * (a[7] + s1.w) + b3[7], 0.0f);
        if (sub == 0) {
            float p = bp[0];
#pragma unroll
            for (int j = 0; j < HDIM; ++j) p += h[j] * Wp[j];
            out[i] = p;
        }
    }
    int w = t >> 6, lane = t & 63;
#pragma unroll
    for (int j = 0; j < HDIM; ++j) {
        float sj = (sub == 0) ? h[j] : 0.0f;
#pragma unroll
        for (int o = 32; o > 0; o >>= 1) sj += __shfl_down(sj, o);
        if (lane == 0) red[w][j] = sj;
    }
    __syncthreads();
    if (t < HDIM)
        partial[(size_t)blockIdx.x * HDIM + t] =
            red[0][t] + red[1][t] + red[2][t] + red[3][t];
}

// ---- value head: reduce per-block partials ----
__global__ void k_value(const float* __restrict__ partial, int nblocks,
                        const float* __restrict__ Wv, const float* __restrict__ bv,
                        float* __restrict__ out, int n) {
    __shared__ float red[256];
    int t = threadIdx.x;
    int j = t & 7, c = t >> 3;
    float v = 0.0f;
    for (int b = c; b < nblocks; b += 32) v += partial[(size_t)b * HDIM + j];
    red[t] = v;
    __syncthreads();
    for (int d = 128; d >= 8; d >>= 1) {
        if (t < d) red[t] += red[t + d];
        __syncthreads();
    }
    if (t == 0) {
        float val = bv[0];
        float inv_n = 1.0f / (float)n;
#pragma unroll
        for (int jj = 0; jj < HDIM; ++jj) val += (red[jj] * inv_n) * Wv[jj];
        out[n] = val;
    }
}

extern "C" void kernel_launch(void* const* d_in, const int* in_sizes, int n_in,
                              void* d_out, int out_size, void* d_ws, size_t ws_size,
                              hipStream_t stream) {
    const float* x  = (const float*)d_in[0];
    const int*   ei = (const int*)d_in[1];
    const float* W1 = (const float*)d_in[2];
    const float* b1 = (const float*)d_in[3];
    const float* W2 = (const float*)d_in[4];
    const float* b2 = (const float*)d_in[5];
    const float* W3 = (const float*)d_in[6];
    const float* b3 = (const float*)d_in[7];
    const float* Wp = (const float*)d_in[8];
    const float* bp = (const float*)d_in[9];
    const float* Wv = (const float*)d_in[10];
    const float* bv = (const float*)d_in[11];

    const int n = in_sizes[0] / 128;
    const int E = in_sizes[1] / 2;
    const int* row = ei;       // edge_index[0] = source
    const int* col = ei + E;   // edge_index[1] = target
    const int nbuck = (n + BSZ - 1) >> BSH;    // 98

    // workspace layout (4-byte units); ~39 MB total
    int*      bhist = (int*)d_ws;                   // 128
    int*      bbase = bhist + 256;                  // 129
    int*      bcur  = bhist + 512;                  // 128 (pad to 1024)
    float*    dis   = (float*)(bhist + 1024);       // n
    int*      deg   = (int*)(dis + n);              // n
    unsigned* bedge = (unsigned*)(deg + n);         // E  (becomes perm in place)
    int*      scur  = (int*)(bedge + E);            // nbuck*NS*BSZ
    int*      cnt   = scur + (size_t)nbuck * NS * BSZ;
    float*    g_a   = (float*)(cnt + (size_t)nbuck * NS * BSZ);  // n*8
    float*    g_b   = g_a + (size_t)n * HDIM;       // n*8
    float*    partial = g_b + (size_t)n * HDIM;     // ceil(n/64)*8
    int*      perm  = (int*)bedge;

    dim3 blk(256);
    dim3 grid_n4(((size_t)n * 4 + 255) / 256);
    dim3 grid_e((E + 256 * EPB - 1) / (256 * EPB));
    dim3 grid_eb((E + 256 * EPB_B - 1) / (256 * EPB_B));
    dim3 grid_sc(nbuck * NS);
    dim3 grid_f((n + 63) / 64);
    const int nblocks3 = (n + 63) / 64;

    k_zero  <<<dim3((n + 255) / 256), blk, 0, stream>>>(deg, bhist, n, nbuck);
    k_bhist <<<grid_e, blk, 0, stream>>>(col, E, nbuck, bhist);
    k_bscan <<<dim3(1), dim3(NBMAX), 0, stream>>>(bhist, nbuck, bbase, bcur);
    k_bucket<<<grid_eb, blk, 0, stream>>>(row, col, E, nbuck, bcur, bedge);
    k_sortchunk<<<grid_sc, blk, 0, stream>>>(bbase, bedge, scur, cnt, deg);
    k_proj1 <<<grid_n4, blk, 0, stream>>>(x, W1, deg, dis, g_a, n);

    k_flayer<<<grid_f, blk, 0, stream>>>(scur, cnt, perm, g_a, g_b, dis, b1, W2, n);
    k_flayer<<<grid_f, blk, 0, stream>>>(scur, cnt, perm, g_b, g_a, dis, b2, W3, n);
    k_flayer3<<<grid_f, blk, 0, stream>>>(scur, cnt, perm, g_a, dis, b3, Wp, bp,
                                          (float*)d_out, partial, n);
    k_value <<<dim3(1), blk, 0, stream>>>(partial, nblocks3, Wv, bv,
                                          (float*)d_out, n);
}